// Round 6
// baseline (340.881 us; speedup 1.0000x reference)
//
#include <hip/hip_runtime.h>
#include <hip/hip_bf16.h>

#define HEADS  16
#define DHEAD  64
#define BATCH  4
#define SEQ    2048
#define DIM    1024
#define KVROWS 2112   // 2049 (null + SEQ) padded up to multiple of 64

typedef __hip_bfloat16 bf16;
typedef __attribute__((ext_vector_type(8))) short s8v;   // 8 x bf16 (4 VGPRs)
typedef __attribute__((ext_vector_type(4))) short s4v;   // 4 x bf16
typedef __attribute__((ext_vector_type(4))) float f4v;   // MFMA accumulator

// split-j bookkeeping: per (b,h): qt 0..14 -> 1 split, 15..30 -> 2, 31 -> 3.
// 50 slots per (b,h), 3200 total. Slots 0..1899 in region A, rest in region B.
__device__ __forceinline__ int qt_base(int qt) {
  return qt <= 14 ? qt : (qt <= 30 ? 15 + 2 * (qt - 15) : 47);
}
__device__ __forceinline__ int qt_nsplit(int qt) {
  return qt <= 14 ? 1 : (qt <= 30 ? 2 : 3);
}

// ---------------------------------------------------------------------------
// fp32 -> bf16 bulk convert (8 elements/thread)
// ---------------------------------------------------------------------------
__global__ void convert_kernel(const float* __restrict__ in, bf16* __restrict__ out) {
  const size_t i = ((size_t)blockIdx.x * 256 + threadIdx.x) * 8;
  const float4 a = *(const float4*)&in[i];
  const float4 b = *(const float4*)&in[i + 4];
  bf16 v[8] = {__float2bfloat16(a.x), __float2bfloat16(a.y),
               __float2bfloat16(a.z), __float2bfloat16(a.w),
               __float2bfloat16(b.x), __float2bfloat16(b.y),
               __float2bfloat16(b.z), __float2bfloat16(b.w)};
  *(s8v*)&out[i] = *(s8v*)v;
}

// ---------------------------------------------------------------------------
// Transpose+convert: fp32 [R][C] -> bf16 [C][R]; R,C multiples of 32
// ---------------------------------------------------------------------------
__global__ void transpose_kernel(const float* __restrict__ in, bf16* __restrict__ out,
                                 int R, int C) {
  __shared__ bf16 tile[32][33];
  const int c0 = blockIdx.x * 32, r0 = blockIdx.y * 32;
  const int tx = threadIdx.x, ty = threadIdx.y;
#pragma unroll
  for (int i = 0; i < 32; i += 8)
    tile[ty + i][tx] = __float2bfloat16(in[(size_t)(r0 + ty + i) * C + c0 + tx]);
  __syncthreads();
#pragma unroll
  for (int i = 0; i < 32; i += 8)
    out[(size_t)(c0 + ty + i) * R + r0 + tx] = tile[tx][ty + i];
}

// ---------------------------------------------------------------------------
// Big GEMM: C = alpha * A[M][K] @ BT[N][K]^T, 128x128 tile, BK=32, 4 waves.
// ---------------------------------------------------------------------------
template <typename OT>
__global__ __launch_bounds__(256) void gemm128_kernel(
    const bf16* __restrict__ A, const bf16* __restrict__ BT,
    OT* __restrict__ C, int K, int c_ld, float alpha) {
  __shared__ bf16 As[128][36];
  __shared__ bf16 Bs[128][36];
  const int m0 = blockIdx.x * 128, n0 = blockIdx.y * 128;
  const int t = threadIdx.x;
  const int w = t >> 6, l = t & 63, lr = l & 15, lq = l >> 4;
  const int wm = (w & 1) * 64, wn = (w >> 1) * 64;
  f4v acc[4][4] = {};
  const int srow = t >> 1, scol = (t & 1) * 16;

  for (int k0 = 0; k0 < K; k0 += 32) {
    __syncthreads();
    *(s8v*)&As[srow][scol]     = *(const s8v*)&A[(size_t)(m0 + srow) * K + k0 + scol];
    *(s8v*)&As[srow][scol + 8] = *(const s8v*)&A[(size_t)(m0 + srow) * K + k0 + scol + 8];
    *(s8v*)&Bs[srow][scol]     = *(const s8v*)&BT[(size_t)(n0 + srow) * K + k0 + scol];
    *(s8v*)&Bs[srow][scol + 8] = *(const s8v*)&BT[(size_t)(n0 + srow) * K + k0 + scol + 8];
    __syncthreads();
    s8v a[4], b[4];
#pragma unroll
    for (int mt = 0; mt < 4; mt++) a[mt] = *(const s8v*)&As[wm + mt * 16 + lr][lq * 8];
#pragma unroll
    for (int ct = 0; ct < 4; ct++) b[ct] = *(const s8v*)&Bs[wn + ct * 16 + lr][lq * 8];
#pragma unroll
    for (int mt = 0; mt < 4; mt++)
#pragma unroll
      for (int ct = 0; ct < 4; ct++)
        acc[mt][ct] = __builtin_amdgcn_mfma_f32_16x16x32_bf16(a[mt], b[ct], acc[mt][ct], 0, 0, 0);
  }
#pragma unroll
  for (int mt = 0; mt < 4; mt++)
#pragma unroll
    for (int ct = 0; ct < 4; ct++)
#pragma unroll
      for (int r = 0; r < 4; r++) {
        const int row = m0 + wm + mt * 16 + lq * 4 + r;
        const int col = n0 + wn + ct * 16 + lr;
        const float v = acc[mt][ct][r] * alpha;
        if constexpr (__is_same(OT, float)) C[(size_t)row * c_ld + col] = v;
        else                                C[(size_t)row * c_ld + col] = __float2bfloat16(v);
      }
}

// ---------------------------------------------------------------------------
// KV GEMM: kv = x @ WkvT^T (N=64), dual-layout epilogue -> kvbuf + kvbufT.
// ---------------------------------------------------------------------------
__global__ __launch_bounds__(256) void gemm_kv_kernel(
    const bf16* __restrict__ A, const bf16* __restrict__ BT,
    bf16* __restrict__ kvbuf, bf16* __restrict__ kvbufT, int K) {
  __shared__ bf16 As[128][32];
  __shared__ bf16 Bs[64][32];
  const int m0 = blockIdx.x * 128;
  const int t = threadIdx.x;
  const int w = t >> 6, l = t & 63, lr = l & 15, lq = l >> 4;
  f4v acc[2][4] = {};
  const int arow = t >> 1, acol = (t & 1) * 16;
  const int brow = t >> 2, bcol = (t & 3) * 8;

  for (int k0 = 0; k0 < K; k0 += 32) {
    __syncthreads();
    *(s8v*)&As[arow][acol]     = *(const s8v*)&A[(size_t)(m0 + arow) * K + k0 + acol];
    *(s8v*)&As[arow][acol + 8] = *(const s8v*)&A[(size_t)(m0 + arow) * K + k0 + acol + 8];
    *(s8v*)&Bs[brow][bcol]     = *(const s8v*)&BT[(size_t)brow * K + k0 + bcol];
    __syncthreads();
    s8v a0 = *(const s8v*)&As[w * 32 + lr][lq * 8];
    s8v a1 = *(const s8v*)&As[w * 32 + 16 + lr][lq * 8];
#pragma unroll
    for (int ct = 0; ct < 4; ct++) {
      s8v bf = *(const s8v*)&Bs[ct * 16 + lr][lq * 8];
      acc[0][ct] = __builtin_amdgcn_mfma_f32_16x16x32_bf16(a0, bf, acc[0][ct], 0, 0, 0);
      acc[1][ct] = __builtin_amdgcn_mfma_f32_16x16x32_bf16(a1, bf, acc[1][ct], 0, 0, 0);
    }
  }
#pragma unroll
  for (int mt = 0; mt < 2; mt++)
#pragma unroll
    for (int ct = 0; ct < 4; ct++)
#pragma unroll
      for (int r = 0; r < 4; r++) {
        const int m = m0 + w * 32 + mt * 16 + lq * 4 + r;
        const int col = ct * 16 + lr;
        const int bb = m >> 11, jj = (m & 2047) + 1;
        const bf16 v = __float2bfloat16(acc[mt][ct][r]);
        kvbuf [(size_t)(bb * KVROWS + jj) * DHEAD + col] = v;
        kvbufT[(size_t)(bb * DHEAD + col) * KVROWS + jj] = v;
      }
}

// ---------------------------------------------------------------------------
// Fill row 0 (null_kv) and tail rows 2049..2111 (zeros) in BOTH kv layouts.
// ---------------------------------------------------------------------------
__global__ void fill_null_tail_kernel(const float* __restrict__ null_kv,
                                      bf16* __restrict__ kvbuf,
                                      bf16* __restrict__ kvbufT) {
  const int idx = blockIdx.x * 256 + threadIdx.x;
  const int d = idx & 63;
  const int s = (idx >> 6) & 63;
  const int b = idx >> 12;
  const int row = (s == 0) ? 0 : 2048 + s;
  const bf16 v = (s == 0) ? __float2bfloat16(null_kv[d]) : __float2bfloat16(0.f);
  kvbuf [(size_t)(b * KVROWS + row) * DHEAD + d] = v;
  kvbufT[(size_t)(b * DHEAD + d) * KVROWS + row] = v;
}

// ---------------------------------------------------------------------------
// Split-j flash attention pass 1: block = (b,h,qt,split), BM=64 q-rows,
// <=16 j-tiles per block (balanced). Emits unnormalized partial O ([64][64]
// bf16) + per-row (m,l) fp32. S^T = KV.Q^T, O^T = KV^T.P^T; kvsT staged from
// pre-transposed global. Wave-uniform mask skip off the diagonal.
// ---------------------------------------------------------------------------
__global__ __launch_bounds__(256) void attn_part_kernel(
    const bf16* __restrict__ q,    // [B*SEQ][DIM] (pre-scaled by 0.125*log2e)
    const bf16* __restrict__ kv,   // [B][KVROWS][64]
    const bf16* __restrict__ kvT,  // [B][64][KVROWS]
    bf16* __restrict__ pOA, bf16* __restrict__ pOB, float* __restrict__ pml) {
  __shared__ bf16 kvs [64][72];
  __shared__ bf16 kvsT[64][72];
  __shared__ bf16 Ps[4][16][72];
  const int t = threadIdx.x, w = t >> 6, l = t & 63, lr = l & 15, lq = l >> 4;
  const int blk = blockIdx.x;
  const int bh = blk / 96, qs = blk % 96;
  const int qt = 31 - qs / 3, split = qs % 3;
  const int ns = qt_nsplit(qt);
  if (split >= ns) return;
  const int h = bh >> 2, b = bh & 3;
  const int q0 = qt * 64;
  const int ntiles = qt + 2;
  const int tper = (ntiles + ns - 1) / ns;
  const int tstart = split * tper;
  const int tend = min(tstart + tper, ntiles);

  const int slot = bh * 50 + qt_base(qt) + split;
  bf16* pO = (slot < 1900) ? (pOA + (size_t)slot * 4096)
                           : (pOB + (size_t)(slot - 1900) * 4096);
  float* ml = pml + (size_t)slot * 128;

  const bf16* qrow = q + ((size_t)(b * SEQ) + q0 + w * 16 + lr) * DIM + h * DHEAD;
  const s8v qb0 = *(const s8v*)&qrow[lq * 8];
  const s8v qb1 = *(const s8v*)&qrow[32 + lq * 8];

  f4v oaccT[4] = {};
  float m_i = -1e30f, l_i = 0.f;
  const bf16* kvb  = kv  + (size_t)b * KVROWS * DHEAD;
  const bf16* kvTb = kvT + (size_t)b * DHEAD * KVROWS;
  const int srow = t >> 2, scol = (t & 3) * 16;
  const int iw = q0 + w * 16 + lr;

  for (int jt0 = tstart; jt0 < tend; jt0++) {
    const int j0 = jt0 * 64;
    __syncthreads();
    *(s8v*)&kvs[srow][scol]      = *(const s8v*)&kvb[(size_t)(j0 + srow) * DHEAD + scol];
    *(s8v*)&kvs[srow][scol + 8]  = *(const s8v*)&kvb[(size_t)(j0 + srow) * DHEAD + scol + 8];
    *(s8v*)&kvsT[srow][scol]     = *(const s8v*)&kvTb[(size_t)srow * KVROWS + j0 + scol];
    *(s8v*)&kvsT[srow][scol + 8] = *(const s8v*)&kvTb[(size_t)srow * KVROWS + j0 + scol + 8];
    __syncthreads();

    // S^T[j][i]
    f4v st[4];
#pragma unroll
    for (int jt = 0; jt < 4; jt++) {
      f4v z = {0.f, 0.f, 0.f, 0.f};
      s8v a0 = *(const s8v*)&kvs[jt * 16 + lr][lq * 8];
      s8v a1 = *(const s8v*)&kvs[jt * 16 + lr][32 + lq * 8];
      z = __builtin_amdgcn_mfma_f32_16x16x32_bf16(a0, qb0, z, 0, 0, 0);
      z = __builtin_amdgcn_mfma_f32_16x16x32_bf16(a1, qb1, z, 0, 0, 0);
      st[jt] = z;
    }

    // mask (diagonal tiles only; wave-uniform branch) + row max
    float mx = -1e30f;
    if (j0 + 62 > q0 + w * 16) {
#pragma unroll
      for (int jt = 0; jt < 4; jt++)
#pragma unroll
        for (int r = 0; r < 4; r++) {
          const int jg = j0 + jt * 16 + lq * 4 + r;
          float v = (jg > iw + 1) ? -1e30f : st[jt][r];
          st[jt][r] = v;
          mx = fmaxf(mx, v);
        }
    } else {
#pragma unroll
      for (int jt = 0; jt < 4; jt++)
#pragma unroll
        for (int r = 0; r < 4; r++) mx = fmaxf(mx, st[jt][r]);
    }
    mx = fmaxf(mx, __shfl_xor(mx, 16));
    mx = fmaxf(mx, __shfl_xor(mx, 32));
    const float mnew = fmaxf(m_i, mx);
    const float alpha = exp2f(m_i - mnew);
    m_i = mnew;
    float rs = 0.f;
#pragma unroll
    for (int jt = 0; jt < 4; jt++)
#pragma unroll
      for (int r = 0; r < 4; r++) {
        const float pv = exp2f(st[jt][r] - mnew);
        st[jt][r] = pv;
        rs += pv;
      }
    rs += __shfl_xor(rs, 16);
    rs += __shfl_xor(rs, 32);
    l_i = l_i * alpha + rs;
#pragma unroll
    for (int dt = 0; dt < 4; dt++)
#pragma unroll
      for (int r = 0; r < 4; r++) oaccT[dt][r] *= alpha;

    // P^T -> Ps[w] (wave-local), b64 writes
#pragma unroll
    for (int jt = 0; jt < 4; jt++) {
      s4v pk;
#pragma unroll
      for (int r = 0; r < 4; r++) {
        bf16 h16 = __float2bfloat16(st[jt][r]);
        pk[r] = *(short*)&h16;
      }
      *(s4v*)&Ps[w][lr][jt * 16 + lq * 4] = pk;
    }

    // O^T[d][i] += sum_j kv^T[d][j] * P^T[j][i]
    const s8v pb0 = *(const s8v*)&Ps[w][lr][lq * 8];
    const s8v pb1 = *(const s8v*)&Ps[w][lr][32 + lq * 8];
#pragma unroll
    for (int dt = 0; dt < 4; dt++) {
      s8v a0 = *(const s8v*)&kvsT[dt * 16 + lr][lq * 8];
      s8v a1 = *(const s8v*)&kvsT[dt * 16 + lr][32 + lq * 8];
      oaccT[dt] = __builtin_amdgcn_mfma_f32_16x16x32_bf16(a0, pb0, oaccT[dt], 0, 0, 0);
      oaccT[dt] = __builtin_amdgcn_mfma_f32_16x16x32_bf16(a1, pb1, oaccT[dt], 0, 0, 0);
    }
  }

  // epilogue: unnormalized O^T -> wave-local LDS transpose -> partial store
#pragma unroll
  for (int dt = 0; dt < 4; dt++) {
    s4v pk;
#pragma unroll
    for (int r = 0; r < 4; r++) {
      bf16 h16 = __float2bfloat16(oaccT[dt][r]);
      pk[r] = *(short*)&h16;
    }
    *(s4v*)&Ps[w][lr][dt * 16 + lq * 4] = pk;  // Ps[w][i][d] = O-unnorm
  }
  const int orow = l >> 2, od = (l & 3) * 16;
  s8v o0 = *(const s8v*)&Ps[w][orow][od];
  s8v o1 = *(const s8v*)&Ps[w][orow][od + 8];
  bf16* op = pO + (size_t)(w * 16 + orow) * 64 + od;
  *(s8v*)&op[0] = o0;
  *(s8v*)&op[8] = o1;
  if (lq == 0) {
    ml[w * 16 + lr] = m_i;
    ml[64 + w * 16 + lr] = l_i;
  }
}

// ---------------------------------------------------------------------------
// Split-j pass 2: combine <=3 partials per (b,h,qt,row) and normalize.
// Block = (bh,qt); thread t: row = t>>2, 16-wide d segment = (t&3)*16.
// ---------------------------------------------------------------------------
__global__ __launch_bounds__(256) void attn_combine_kernel(
    const bf16* __restrict__ pOA, const bf16* __restrict__ pOB,
    const float* __restrict__ pml, bf16* __restrict__ o) {
  const int blk = blockIdx.x;             // 2048 = bh*32 + qt
  const int bh = blk >> 5, qt = blk & 31;
  const int h = bh >> 2, b = bh & 3;
  const int t = threadIdx.x;
  const int row = t >> 2, dseg = (t & 3) * 16;
  const int ns = qt_nsplit(qt), sbase = bh * 50 + qt_base(qt);

  float m_s[3], l_s[3], M = -1e30f;
  for (int s = 0; s < ns; s++) {
    m_s[s] = pml[(size_t)(sbase + s) * 128 + row];
    l_s[s] = pml[(size_t)(sbase + s) * 128 + 64 + row];
    M = fmaxf(M, m_s[s]);
  }
  float L = 0.f, acc[16] = {};
  for (int s = 0; s < ns; s++) {
    const float wgt = exp2f(m_s[s] - M);
    L += wgt * l_s[s];
    const int slot = sbase + s;
    const bf16* pO = (slot < 1900) ? (pOA + (size_t)slot * 4096)
                                   : (pOB + (size_t)(slot - 1900) * 4096);
    const bf16* prow = pO + row * 64 + dseg;
    s8v v0 = *(const s8v*)&prow[0];
    s8v v1 = *(const s8v*)&prow[8];
    const bf16* pb0 = (const bf16*)&v0;
    const bf16* pb1 = (const bf16*)&v1;
#pragma unroll
    for (int e = 0; e < 8; e++) acc[e]     += wgt * __bfloat162float(pb0[e]);
#pragma unroll
    for (int e = 0; e < 8; e++) acc[8 + e] += wgt * __bfloat162float(pb1[e]);
  }
  const float inv = 1.f / L;
  bf16 outv[16];
#pragma unroll
  for (int e = 0; e < 16; e++) outv[e] = __float2bfloat16(acc[e] * inv);
  bf16* op = o + ((size_t)(b * SEQ) + qt * 64 + row) * DIM + h * DHEAD + dseg;
  *(s8v*)&op[0] = *(const s8v*)&outv[0];
  *(s8v*)&op[8] = *(const s8v*)&outv[8];
}

// ---------------------------------------------------------------------------
// Memory plan. Inputs fp32, output fp32 (32 MB d_out).
// d_out during pipeline: q(bf16)@0..16MB | kvbufT@16MB (1.03MB) |
//   pOB@17.06MB (10.65MB, partial-O slots 1900+) | pml@27.71MB (1.64MB)
//   -- all dead before final fp32 GEMM writes d_out.
// ws (35.1MB proven): att@0 16MB (WqT/WkvT alias it pre-attn) |
//   pOA@16MB (15.56MB, partial-O slots 0..1899; xb aliases it pre-attn) |
//   WoutT@32MB 2MB | kvbuf@34MB 1.06MB.
// ---------------------------------------------------------------------------
extern "C" void kernel_launch(void* const* d_in, const int* in_sizes, int n_in,
                              void* d_out, int out_size, void* d_ws, size_t ws_size,
                              hipStream_t stream) {
  const float* x       = (const float*)d_in[0];
  const float* Wq      = (const float*)d_in[1];
  const float* Wkv     = (const float*)d_in[2];
  const float* null_kv = (const float*)d_in[3];
  const float* Wout    = (const float*)d_in[4];
  float* out = (float*)d_out;

  char* dob = (char*)d_out;
  bf16*  q      = (bf16*)dob;                                       // 16 MB
  bf16*  kvbufT = (bf16*)(dob + (size_t)16 * 1024 * 1024);          // 1.03 MB
  bf16*  pOB    = (bf16*)(dob + (size_t)16 * 1024 * 1024 + 0x110000);
  float* pml    = (float*)(dob + (size_t)16 * 1024 * 1024 + 0x110000
                           + (size_t)1300 * 8192);

  char* p = (char*)d_ws;
  bf16* att   = (bf16*)p;
  bf16* xb    = (bf16*)(p + (size_t)16 * 1024 * 1024);
  bf16* pOA   = xb;  // xb dead before attn pass 1 writes partials
  bf16* WoutT = (bf16*)(p + (size_t)32 * 1024 * 1024);
  bf16* kvbuf = (bf16*)(p + (size_t)34 * 1024 * 1024);
  bf16* WqT   = att;
  bf16* WkvT  = att + (size_t)DIM * DIM;

  convert_kernel<<<(BATCH * SEQ * DIM) / (256 * 8), 256, 0, stream>>>(x, xb);

  const dim3 tb(32, 8);
  transpose_kernel<<<dim3(32, 32), tb, 0, stream>>>(Wq,   WqT,   DIM, DIM);
  transpose_kernel<<<dim3(2, 32),  tb, 0, stream>>>(Wkv,  WkvT,  DIM, DHEAD);
  transpose_kernel<<<dim3(32, 32), tb, 0, stream>>>(Wout, WoutT, DIM, DIM);

  // q = x @ Wq * (DHEAD^-0.5 * log2e) -> bf16 in d_out
  gemm128_kernel<bf16><<<dim3(64, 8), 256, 0, stream>>>(xb, WqT, q, DIM, DIM,
                                                        0.125f * 1.44269504089f);
  gemm_kv_kernel<<<64, 256, 0, stream>>>(xb, WkvT, kvbuf, kvbufT, DIM);
  fill_null_tail_kernel<<<(BATCH * 64 * 64) / 256, 256, 0, stream>>>(null_kv, kvbuf, kvbufT);

  // attention: pass 1 (split-j partials) + pass 2 (combine)
  attn_part_kernel<<<64 * 96, 256, 0, stream>>>(q, kvbuf, kvbufT, pOA, pOB, pml);
  attn_combine_kernel<<<64 * 32, 256, 0, stream>>>(pOA, pOB, pml, att);

  // out = att @ Wout -> d_out fp32 (q, kvbufT, pOB, pml all dead)
  gemm128_kernel<float><<<dim3(64, 8), 256, 0, stream>>>(att, WoutT, out, DIM, DIM, 1.0f);
}

// Round 7
// 257.547 us; speedup vs baseline: 1.3236x; 1.3236x over previous
//
#include <hip/hip_runtime.h>
#include <hip/hip_bf16.h>

#define HEADS  16
#define DHEAD  64
#define BATCH  4
#define SEQ    2048
#define DIM    1024
#define KVROWS 2112   // 2049 (null + SEQ) padded up to multiple of 64

typedef __hip_bfloat16 bf16;
typedef __attribute__((ext_vector_type(8))) short s8v;   // 8 x bf16 (4 VGPRs)
typedef __attribute__((ext_vector_type(4))) short s4v;   // 4 x bf16
typedef __attribute__((ext_vector_type(4))) float f4v;   // MFMA accumulator

// async global->LDS, 16B per lane, dest = wave-uniform base + lane*16
__device__ __forceinline__ void gl_lds16(const void* g, void* l) {
  __builtin_amdgcn_global_load_lds(
      (const __attribute__((address_space(1))) unsigned int*)g,
      (__attribute__((address_space(3))) unsigned int*)l, 16, 0, 0);
}

// ---------------------------------------------------------------------------
// fp32 -> bf16 bulk convert (8 elements/thread)
// ---------------------------------------------------------------------------
__global__ void convert_kernel(const float* __restrict__ in, bf16* __restrict__ out) {
  const size_t i = ((size_t)blockIdx.x * 256 + threadIdx.x) * 8;
  const float4 a = *(const float4*)&in[i];
  const float4 b = *(const float4*)&in[i + 4];
  bf16 v[8] = {__float2bfloat16(a.x), __float2bfloat16(a.y),
               __float2bfloat16(a.z), __float2bfloat16(a.w),
               __float2bfloat16(b.x), __float2bfloat16(b.y),
               __float2bfloat16(b.z), __float2bfloat16(b.w)};
  *(s8v*)&out[i] = *(s8v*)v;
}

// ---------------------------------------------------------------------------
// Transpose+convert: fp32 [R][C] -> bf16 [C][R]; R,C multiples of 32
// ---------------------------------------------------------------------------
__global__ void transpose_kernel(const float* __restrict__ in, bf16* __restrict__ out,
                                 int R, int C) {
  __shared__ bf16 tile[32][33];
  const int c0 = blockIdx.x * 32, r0 = blockIdx.y * 32;
  const int tx = threadIdx.x, ty = threadIdx.y;
#pragma unroll
  for (int i = 0; i < 32; i += 8)
    tile[ty + i][tx] = __float2bfloat16(in[(size_t)(r0 + ty + i) * C + c0 + tx]);
  __syncthreads();
#pragma unroll
  for (int i = 0; i < 32; i += 8)
    out[(size_t)(c0 + ty + i) * R + r0 + tx] = tile[tx][ty + i];
}

// ---------------------------------------------------------------------------
// m97-style async GEMM: C = alpha * A[M][K] @ BT[N][K]^T. 128x128 tile,
// BK=32, 4 waves (2x2, 64x64 each, 4x4 MFMA 16x16x32 frags).
// Staging: global_load_lds width=16 into UNPADDED [128][32]-short tiles.
// Bank swizzle is embedded in the per-lane GLOBAL address: LDS row r holds
// its 4 16B-chunks permuted by chunk' = chunk ^ ((r>>1)&3). Staging writes
// are lane-ordered (conflict-free); b128 frag reads hit 2 lanes/bank (free).
// ---------------------------------------------------------------------------
template <typename OT>
__global__ __launch_bounds__(256) void gemm_async_kernel(
    const bf16* __restrict__ A, const bf16* __restrict__ BT,
    OT* __restrict__ C, int K, int c_ld, float alpha) {
  __shared__ bf16 As[128 * 32];  // 8 KB
  __shared__ bf16 Bs[128 * 32];  // 8 KB
  const int m0 = blockIdx.x * 128, n0 = blockIdx.y * 128;
  const int t = threadIdx.x;
  const int w = t >> 6, l = t & 63, lr = l & 15, lq = l >> 4;
  const int wm = (w & 1) * 64, wn = (w >> 1) * 64;
  f4v acc[4][4] = {};

  // staging: wave w loads 16-row groups {2w, 2w+1} of A and of B.
  // lane l -> row (l>>2), chunk-slot (l&3); global chunk = (l&3) ^ ((l>>3)&3).
  const int rowl = l >> 2;
  const int cl = ((l & 3) ^ ((l >> 3) & 3)) * 8;
  const bf16* gA0 = A  + (size_t)(m0 + 32 * w + rowl) * K + cl;
  const bf16* gA1 = A  + (size_t)(m0 + 32 * w + 16 + rowl) * K + cl;
  const bf16* gB0 = BT + (size_t)(n0 + 32 * w + rowl) * K + cl;
  const bf16* gB1 = BT + (size_t)(n0 + 32 * w + 16 + rowl) * K + cl;
  bf16* lA0 = As + (2 * w) * 512;      // 512 shorts = 1 KB = 16 rows
  bf16* lA1 = As + (2 * w + 1) * 512;
  bf16* lB0 = Bs + (2 * w) * 512;
  bf16* lB1 = Bs + (2 * w + 1) * 512;

  const int sw = lq ^ ((lr >> 1) & 3);  // frag-read chunk swizzle
  const s8v* As16 = (const s8v*)As;
  const s8v* Bs16 = (const s8v*)Bs;

  for (int k0 = 0; k0 < K; k0 += 32) {
    __syncthreads();
    gl_lds16(gA0 + k0, lA0);
    gl_lds16(gA1 + k0, lA1);
    gl_lds16(gB0 + k0, lB0);
    gl_lds16(gB1 + k0, lB1);
    __syncthreads();  // drains vmcnt -> LDS valid
    s8v a[4], b[4];
#pragma unroll
    for (int mt = 0; mt < 4; mt++) a[mt] = As16[(wm + mt * 16 + lr) * 4 + sw];
#pragma unroll
    for (int ct = 0; ct < 4; ct++) b[ct] = Bs16[(wn + ct * 16 + lr) * 4 + sw];
#pragma unroll
    for (int mt = 0; mt < 4; mt++)
#pragma unroll
      for (int ct = 0; ct < 4; ct++)
        acc[mt][ct] = __builtin_amdgcn_mfma_f32_16x16x32_bf16(a[mt], b[ct], acc[mt][ct], 0, 0, 0);
  }
#pragma unroll
  for (int mt = 0; mt < 4; mt++)
#pragma unroll
    for (int ct = 0; ct < 4; ct++)
#pragma unroll
      for (int r = 0; r < 4; r++) {
        const int row = m0 + wm + mt * 16 + lq * 4 + r;
        const int col = n0 + wn + ct * 16 + lr;
        const float v = acc[mt][ct][r] * alpha;
        if constexpr (__is_same(OT, float)) C[(size_t)row * c_ld + col] = v;
        else                                C[(size_t)row * c_ld + col] = __float2bfloat16(v);
      }
}

// ---------------------------------------------------------------------------
// KV GEMM: kv = x @ WkvT^T (N=64), dual-layout epilogue -> kvbuf + kvbufT.
// ---------------------------------------------------------------------------
__global__ __launch_bounds__(256) void gemm_kv_kernel(
    const bf16* __restrict__ A, const bf16* __restrict__ BT,
    bf16* __restrict__ kvbuf, bf16* __restrict__ kvbufT, int K) {
  __shared__ bf16 As[128][32];
  __shared__ bf16 Bs[64][32];
  const int m0 = blockIdx.x * 128;
  const int t = threadIdx.x;
  const int w = t >> 6, l = t & 63, lr = l & 15, lq = l >> 4;
  f4v acc[2][4] = {};
  const int arow = t >> 1, acol = (t & 1) * 16;
  const int brow = t >> 2, bcol = (t & 3) * 8;

  for (int k0 = 0; k0 < K; k0 += 32) {
    __syncthreads();
    *(s8v*)&As[arow][acol]     = *(const s8v*)&A[(size_t)(m0 + arow) * K + k0 + acol];
    *(s8v*)&As[arow][acol + 8] = *(const s8v*)&A[(size_t)(m0 + arow) * K + k0 + acol + 8];
    *(s8v*)&Bs[brow][bcol]     = *(const s8v*)&BT[(size_t)brow * K + k0 + bcol];
    __syncthreads();
    s8v a0 = *(const s8v*)&As[w * 32 + lr][lq * 8];
    s8v a1 = *(const s8v*)&As[w * 32 + 16 + lr][lq * 8];
#pragma unroll
    for (int ct = 0; ct < 4; ct++) {
      s8v bf = *(const s8v*)&Bs[ct * 16 + lr][lq * 8];
      acc[0][ct] = __builtin_amdgcn_mfma_f32_16x16x32_bf16(a0, bf, acc[0][ct], 0, 0, 0);
      acc[1][ct] = __builtin_amdgcn_mfma_f32_16x16x32_bf16(a1, bf, acc[1][ct], 0, 0, 0);
    }
  }
#pragma unroll
  for (int mt = 0; mt < 2; mt++)
#pragma unroll
    for (int ct = 0; ct < 4; ct++)
#pragma unroll
      for (int r = 0; r < 4; r++) {
        const int m = m0 + w * 32 + mt * 16 + lq * 4 + r;
        const int col = ct * 16 + lr;
        const int bb = m >> 11, jj = (m & 2047) + 1;
        const bf16 v = __float2bfloat16(acc[mt][ct][r]);
        kvbuf [(size_t)(bb * KVROWS + jj) * DHEAD + col] = v;
        kvbufT[(size_t)(bb * DHEAD + col) * KVROWS + jj] = v;
      }
}

// ---------------------------------------------------------------------------
// Fill row 0 (null_kv) and tail rows 2049..2111 (zeros) in BOTH kv layouts.
// ---------------------------------------------------------------------------
__global__ void fill_null_tail_kernel(const float* __restrict__ null_kv,
                                      bf16* __restrict__ kvbuf,
                                      bf16* __restrict__ kvbufT) {
  const int idx = blockIdx.x * 256 + threadIdx.x;
  const int d = idx & 63;
  const int s = (idx >> 6) & 63;
  const int b = idx >> 12;
  const int row = (s == 0) ? 0 : 2048 + s;
  const bf16 v = (s == 0) ? __float2bfloat16(null_kv[d]) : __float2bfloat16(0.f);
  kvbuf [(size_t)(b * KVROWS + row) * DHEAD + d] = v;
  kvbufT[(size_t)(b * DHEAD + d) * KVROWS + row] = v;
}

// ---------------------------------------------------------------------------
// Transposed flash attention (r4 winner + kvbufT staging + mask-skip branch).
// BM=64 q-rows/block, monolithic j-loop, longest q-tiles dispatched first.
// S^T = KV.Q^T; O^T = KV^T.P^T (KV^T pre-transposed in global). All loop LDS
// traffic b128/b64 on 72-short-padded rows. exp2-domain softmax.
// ---------------------------------------------------------------------------
__global__ __launch_bounds__(256) void attn_kernel(
    const bf16* __restrict__ q,    // [B*SEQ][DIM] (pre-scaled by 0.125*log2e)
    const bf16* __restrict__ kv,   // [B][KVROWS][64]
    const bf16* __restrict__ kvT,  // [B][64][KVROWS]
    bf16* __restrict__ o) {        // [B*SEQ][DIM]
  __shared__ bf16 kvs [64][72];
  __shared__ bf16 kvsT[64][72];
  __shared__ bf16 Ps[4][16][72];
  const int t = threadIdx.x, w = t >> 6, l = t & 63, lr = l & 15, lq = l >> 4;
  const int blk = blockIdx.x;
  const int qt = 31 - (blk >> 6);          // longest first
  const int hb = blk & 63, h = hb >> 2, b = hb & 3;
  const int q0 = qt * 64;
  const int iw = q0 + w * 16 + lr;

  const bf16* qrow = q + ((size_t)(b * SEQ) + iw) * DIM + h * DHEAD;
  const s8v qb0 = *(const s8v*)&qrow[lq * 8];
  const s8v qb1 = *(const s8v*)&qrow[32 + lq * 8];

  f4v oaccT[4] = {};
  float m_i = -1e30f, l_i = 0.f;
  const bf16* kvb  = kv  + (size_t)b * KVROWS * DHEAD;
  const bf16* kvTb = kvT + (size_t)b * DHEAD * KVROWS;
  const int jend = q0 + 65;
  const int srow = t >> 2, scol = (t & 3) * 16;

  for (int j0 = 0; j0 < jend; j0 += 64) {
    __syncthreads();
    *(s8v*)&kvs[srow][scol]      = *(const s8v*)&kvb[(size_t)(j0 + srow) * DHEAD + scol];
    *(s8v*)&kvs[srow][scol + 8]  = *(const s8v*)&kvb[(size_t)(j0 + srow) * DHEAD + scol + 8];
    *(s8v*)&kvsT[srow][scol]     = *(const s8v*)&kvTb[(size_t)srow * KVROWS + j0 + scol];
    *(s8v*)&kvsT[srow][scol + 8] = *(const s8v*)&kvTb[(size_t)srow * KVROWS + j0 + scol + 8];
    __syncthreads();

    // S^T[j][i]
    f4v st[4];
#pragma unroll
    for (int jt = 0; jt < 4; jt++) {
      f4v z = {0.f, 0.f, 0.f, 0.f};
      s8v a0 = *(const s8v*)&kvs[jt * 16 + lr][lq * 8];
      s8v a1 = *(const s8v*)&kvs[jt * 16 + lr][32 + lq * 8];
      z = __builtin_amdgcn_mfma_f32_16x16x32_bf16(a0, qb0, z, 0, 0, 0);
      z = __builtin_amdgcn_mfma_f32_16x16x32_bf16(a1, qb1, z, 0, 0, 0);
      st[jt] = z;
    }

    // mask (diagonal tiles only; wave-uniform branch) + online softmax
    float mx = -1e30f;
    if (j0 + 62 > q0 + w * 16) {
#pragma unroll
      for (int jt = 0; jt < 4; jt++)
#pragma unroll
        for (int r = 0; r < 4; r++) {
          const int jg = j0 + jt * 16 + lq * 4 + r;
          float v = (jg > iw + 1) ? -1e30f : st[jt][r];
          st[jt][r] = v;
          mx = fmaxf(mx, v);
        }
    } else {
#pragma unroll
      for (int jt = 0; jt < 4; jt++)
#pragma unroll
        for (int r = 0; r < 4; r++) mx = fmaxf(mx, st[jt][r]);
    }
    mx = fmaxf(mx, __shfl_xor(mx, 16));
    mx = fmaxf(mx, __shfl_xor(mx, 32));
    const float mnew = fmaxf(m_i, mx);
    const float alpha = exp2f(m_i - mnew);
    m_i = mnew;
    float rs = 0.f;
#pragma unroll
    for (int jt = 0; jt < 4; jt++)
#pragma unroll
      for (int r = 0; r < 4; r++) {
        const float pv = exp2f(st[jt][r] - mnew);
        st[jt][r] = pv;
        rs += pv;
      }
    rs += __shfl_xor(rs, 16);
    rs += __shfl_xor(rs, 32);
    l_i = l_i * alpha + rs;
#pragma unroll
    for (int dt = 0; dt < 4; dt++)
#pragma unroll
      for (int r = 0; r < 4; r++) oaccT[dt][r] *= alpha;

    // P^T -> Ps[w] (wave-local), b64 writes
#pragma unroll
    for (int jt = 0; jt < 4; jt++) {
      s4v pk;
#pragma unroll
      for (int r = 0; r < 4; r++) {
        bf16 h16 = __float2bfloat16(st[jt][r]);
        pk[r] = *(short*)&h16;
      }
      *(s4v*)&Ps[w][lr][jt * 16 + lq * 4] = pk;
    }

    // O^T[d][i] += sum_j kv^T[d][j] * P^T[j][i]
    const s8v pb0 = *(const s8v*)&Ps[w][lr][lq * 8];
    const s8v pb1 = *(const s8v*)&Ps[w][lr][32 + lq * 8];
#pragma unroll
    for (int dt = 0; dt < 4; dt++) {
      s8v a0 = *(const s8v*)&kvsT[dt * 16 + lr][lq * 8];
      s8v a1 = *(const s8v*)&kvsT[dt * 16 + lr][32 + lq * 8];
      oaccT[dt] = __builtin_amdgcn_mfma_f32_16x16x32_bf16(a0, pb0, oaccT[dt], 0, 0, 0);
      oaccT[dt] = __builtin_amdgcn_mfma_f32_16x16x32_bf16(a1, pb1, oaccT[dt], 0, 0, 0);
    }
  }

  // epilogue: O^T -> wave-local LDS transpose -> coalesced 32B stores
  const float inv = 1.0f / l_i;
#pragma unroll
  for (int dt = 0; dt < 4; dt++) {
    s4v pk;
#pragma unroll
    for (int r = 0; r < 4; r++) {
      bf16 h16 = __float2bfloat16(oaccT[dt][r] * inv);
      pk[r] = *(short*)&h16;
    }
    *(s4v*)&Ps[w][lr][dt * 16 + lq * 4] = pk;  // Ps[w][i][d] = O
  }
  const int orow = l >> 2, od = (l & 3) * 16;
  s8v o0 = *(const s8v*)&Ps[w][orow][od];
  s8v o1 = *(const s8v*)&Ps[w][orow][od + 8];
  bf16* op = o + ((size_t)(b * SEQ) + q0 + w * 16 + orow) * DIM + h * DHEAD + od;
  *(s8v*)&op[0] = o0;
  *(s8v*)&op[8] = o1;
}

// ---------------------------------------------------------------------------
// Inputs fp32, output fp32 (32 MB d_out). d_out staging: q(bf16)@0..16MB,
// kvbufT@16MB (1.03MB) — dead before final fp32 GEMM. ws 35.1MB: att@0 16MB
// (WqT@0/WkvT@+2MB alias, dead pre-attn) | xb@16MB | WoutT@32MB | kvbuf@34MB.
// ---------------------------------------------------------------------------
extern "C" void kernel_launch(void* const* d_in, const int* in_sizes, int n_in,
                              void* d_out, int out_size, void* d_ws, size_t ws_size,
                              hipStream_t stream) {
  const float* x       = (const float*)d_in[0];
  const float* Wq      = (const float*)d_in[1];
  const float* Wkv     = (const float*)d_in[2];
  const float* null_kv = (const float*)d_in[3];
  const float* Wout    = (const float*)d_in[4];
  float* out = (float*)d_out;

  char* dob = (char*)d_out;
  bf16* q      = (bf16*)dob;                                // 16 MB
  bf16* kvbufT = (bf16*)(dob + (size_t)16 * 1024 * 1024);   // 1.03 MB
  char* p = (char*)d_ws;
  bf16* att   = (bf16*)p;
  bf16* xb    = (bf16*)(p + (size_t)16 * 1024 * 1024);
  bf16* WoutT = (bf16*)(p + (size_t)32 * 1024 * 1024);
  bf16* kvbuf = (bf16*)(p + (size_t)34 * 1024 * 1024);
  bf16* WqT   = att;
  bf16* WkvT  = att + (size_t)DIM * DIM;

  convert_kernel<<<(BATCH * SEQ * DIM) / (256 * 8), 256, 0, stream>>>(x, xb);

  const dim3 tb(32, 8);
  transpose_kernel<<<dim3(32, 32), tb, 0, stream>>>(Wq,   WqT,   DIM, DIM);
  transpose_kernel<<<dim3(2, 32),  tb, 0, stream>>>(Wkv,  WkvT,  DIM, DHEAD);
  transpose_kernel<<<dim3(32, 32), tb, 0, stream>>>(Wout, WoutT, DIM, DIM);

  // q = x @ Wq * (DHEAD^-0.5 * log2e) -> bf16 in d_out
  gemm_async_kernel<bf16><<<dim3(64, 8), 256, 0, stream>>>(xb, WqT, q, DIM, DIM,
                                                           0.125f * 1.44269504089f);
  gemm_kv_kernel<<<64, 256, 0, stream>>>(xb, WkvT, kvbuf, kvbufT, DIM);
  fill_null_tail_kernel<<<(BATCH * 64 * 64) / 256, 256, 0, stream>>>(null_kv, kvbuf, kvbufT);

  // attention: monolithic, BM=64, 2048 blocks
  attn_kernel<<<BATCH * HEADS * (SEQ / 64), 256, 0, stream>>>(q, kvbuf, kvbufT, att);

  // out = att @ Wout -> d_out fp32 (q, kvbufT dead)
  gemm_async_kernel<float><<<dim3(64, 8), 256, 0, stream>>>(att, WoutT, out, DIM, DIM, 1.0f);
}